// Round 2
// baseline (355.928 us; speedup 1.0000x reference)
//
#include <hip/hip_runtime.h>
#include <cstddef>

#define BB   8
#define NN   2048
#define CIN  64
#define COUT 64
#define KK   20
#define KSS  20
#define C2   128   // 2*CIN
#define PPB  8                 // points per block (8 waves of 64)
#define NC   24                // fp32 candidate count for knn refine
#define KT   80                // K-steps of 32 in conv (2560/32)
#define KH   40                // K-steps per wave (K split in halves)
#define AGG_LD 2568            // padded agg row (f16): keeps 16B align, bank spread

typedef _Float16 h2t  __attribute__((ext_vector_type(2)));
typedef _Float16 f16x8 __attribute__((ext_vector_type(8)));
typedef float    f32x4 __attribute__((ext_vector_type(4)));

__device__ __forceinline__ unsigned pk2(float a, float b) {
    unsigned short ua = __builtin_bit_cast(unsigned short, (_Float16)a);
    unsigned short ub = __builtin_bit_cast(unsigned short, (_Float16)b);
    return (unsigned)ua | ((unsigned)ub << 16);
}

// ---------------------------------------------------------------------------
// Prep:
//  aFrag[(mt*KT + t)*64 + l] = 8 f16 of conv_w[16mt + (l&15)][32t + (l>>4)*8 ..+7]
//    (exact A-fragment layout for mfma_f32_16x16x32_f16, M-tile mt)
//  mowT[c*64 + o] = mlp_out_w[o][c]
// ---------------------------------------------------------------------------
__global__ __launch_bounds__(256) void prep_kernel(
    const float* __restrict__ cw, const float* __restrict__ mw,
    uint4* __restrict__ aFrag, float* __restrict__ mowT)
{
    int i = blockIdx.x * 256 + threadIdx.x;
    if (i < 4 * KT * 64) {
        int wv = i / (KT * 64);
        int r  = i - wv * (KT * 64);
        int t  = r >> 6, l = r & 63;
        int o  = (wv << 4) + (l & 15);
        int j  = (t << 5) + ((l >> 4) << 3);
        const float* s = cw + (size_t)o * (C2 * KSS) + j;
        uint4 v;
        v.x = pk2(s[0], s[1]);
        v.y = pk2(s[2], s[3]);
        v.z = pk2(s[4], s[5]);
        v.w = pk2(s[6], s[7]);
        aFrag[i] = v;
    }
    if (i < COUT * CIN) {
        int o = i >> 6, c = i & 63;
        mowT[c * COUT + o] = mw[o * CIN + c];
    }
}

// ---------------------------------------------------------------------------
// FUSED kernel, PPB=8 / 512 threads. Wave-local phases barrier-free; 2
// barriers total. LDS 59.9 KB -> 2 blocks/CU = 16 waves/CU (latency hiding
// for the serial KNN-select shuffle chain was the round-1 bottleneck:
// occupancy 31%, VALUBusy 34%, MfmaUtil 3.4%).
// Conv: M-tile mt = w&3, K-half kh = w>>2, 40 MFMA/wave, 8 valid B columns.
// ---------------------------------------------------------------------------
__global__ __launch_bounds__(512, 4) void point_kernel(
    const float* __restrict__ x,
    const float* __restrict__ feature,
    const float* __restrict__ kern,
    const float* __restrict__ pad,
    const float* __restrict__ mlp_w,
    const float* __restrict__ mlp_b,
    const uint4* __restrict__ aFrag,
    const float* __restrict__ conv_b,
    const float* __restrict__ mowT,
    const float* __restrict__ mob,
    float* __restrict__ out)
{
    __shared__ __align__(16) _Float16 agg_h[PPB][AGG_LD];    // 41088 B
    __shared__ __align__(16) float u_s[PPB * KK * KSS];      // 12800 B (perm|red)
    __shared__ float xr_s[PPB][KK][3];
    __shared__ float xd_s[PPB][KK];
    __shared__ float xrep_s[PPB][3];
    __shared__ float colden_s[PPB][KSS];
    __shared__ float fcol_s[PPB][CIN];
    __shared__ int   nid_s[PPB][KK];

    float (*perm_s)[KK][KSS] = (float (*)[KK][KSS])u_s;
    float (*red_s)[PPB][COUT] = (float (*)[PPB][COUT])u_s;  // [2][8][64] post-B1

    const int tid  = threadIdx.x;
    const int w    = tid >> 6;
    const int lane = tid & 63;
    const int p    = blockIdx.x * PPB + w;
    const int b    = p >> 11;
    const int n    = p & (NN - 1);

    const float* xb0 = x + (size_t)(b * 3 + 0) * NN;
    const float* xb1 = x + (size_t)(b * 3 + 1) * NN;
    const float* xb2 = x + (size_t)(b * 3 + 2) * NN;

    // ================= phase 0: KNN (wave-local, verified v3) =============
    {
        const unsigned long long SENT = 0xFFFFFFFFFFFFFFFFull;
        const float qx = xb0[n], qy = xb1[n], qz = xb2[n];

        float d2r[32];
#pragma unroll
        for (int j = 0; j < 32; ++j) {
            int m = lane + 64 * j;
            float dx = xb0[m] - qx;
            float dy = xb1[m] - qy;
            float dz = xb2[m] - qz;
            d2r[j] = dx * dx + dy * dy + dz * dz;
        }

        unsigned long long c0 = SENT, c1 = SENT, c2 = SENT;
#pragma unroll
        for (int j = 0; j < 32; ++j) {
            unsigned long long pk =
                ((unsigned long long)__float_as_uint(d2r[j]) << 32)
                | (unsigned)(lane + 64 * j);
            if (pk < c0)      { c2 = c1; c1 = c0; c0 = pk; }
            else if (pk < c1) { c2 = c1; c1 = pk; }
            else if (pk < c2) { c2 = pk; }
        }

        unsigned killmask = 0u;
        unsigned long long mypk = SENT;
        for (int k = 0; k < NC; ++k) {
            unsigned long long bp = c0;
#pragma unroll
            for (int off = 32; off > 0; off >>= 1) {
                unsigned long long op_ = __shfl_xor(bp, off);
                if (op_ < bp) bp = op_;
            }
            if (lane == k) mypk = bp;
            if (c0 == bp) {                       // unique owner lane
                killmask |= 1u << ((unsigned)(bp & 0xFFFFFFFFull) >> 6);
                c0 = c1; c1 = c2; c2 = SENT;
                if (c0 == SENT) {                 // rare rescan
#pragma unroll
                    for (int j = 0; j < 32; ++j) {
                        if (!(killmask & (1u << j))) {
                            unsigned long long pk =
                                ((unsigned long long)__float_as_uint(d2r[j]) << 32)
                                | (unsigned)(lane + 64 * j);
                            if (pk < c0)      { c2 = c1; c1 = c0; c0 = pk; }
                            else if (pk < c1) { c2 = c1; c1 = pk; }
                            else if (pk < c2) { c2 = pk; }
                        }
                    }
                }
            }
        }

        double dd = 1e300;
        int ci = 0x7fffffff;
        if (lane < NC) {
            ci = (int)(mypk & 0xFFFFFFFFull);
            double dx = (double)xb0[ci] - (double)qx;
            double dy = (double)xb1[ci] - (double)qy;
            double dz = (double)xb2[ci] - (double)qz;
            dd = dx * dx + dy * dy + dz * dz;
        }
        unsigned long long db = __double_as_longlong(dd);
#pragma unroll
        for (int size = 2; size <= 32; size <<= 1) {
#pragma unroll
            for (int stride = size >> 1; stride > 0; stride >>= 1) {
                unsigned long long odb = __shfl_xor(db, stride);
                int oci = __shfl_xor(ci, stride);
                bool up = ((lane & size) == 0);
                bool takemin = (((lane & stride) == 0) == up);
                bool oless = (odb < db) || (odb == db && oci < ci);
                if (takemin == oless) { db = odb; ci = oci; }
            }
        }
        if (lane < KK) nid_s[w][lane] = ci;     // same-wave producer/consumer
    }

    // ======= per-point pipeline: all wave-local, NO barriers needed =======
    fcol_s[w][lane] = feature[(size_t)(b * CIN + lane) * NN + n];

    if (lane == 0) {
        int m0 = nid_s[w][0];
        xrep_s[w][0] = xb0[m0]; xrep_s[w][1] = xb1[m0]; xrep_s[w][2] = xb2[m0];
    }
    if (lane < KK) {
        int m = nid_s[w][lane];
        float rx = xb0[m] - xrep_s[w][0];
        float ry = xb1[m] - xrep_s[w][1];
        float rz = xb2[m] - xrep_s[w][2];
        xr_s[w][lane][0] = rx; xr_s[w][lane][1] = ry; xr_s[w][lane][2] = rz;
        xd_s[w][lane] = sqrtf(rx * rx + ry * ry + rz * rz + 1e-12f);
    }

    // ---- perm: relu -> colnorm -> square -> colnorm -> >0.1 (wave-local) --
    for (int e = lane; e < KK * KSS; e += 64) {
        int k = e / KSS, m = e % KSS;
        float v = xr_s[w][k][0] * kern[0 * KSS + m]
                + xr_s[w][k][1] * kern[1 * KSS + m]
                + xr_s[w][k][2] * kern[2 * KSS + m]
                + pad[k * KSS + m];
        perm_s[w][k][m] = v > 0.0f ? v : 0.0f;
    }
    if (lane < KSS) {
        float s = 0.0f;
        for (int k = 0; k < KK; ++k) s += perm_s[w][k][lane];
        colden_s[w][lane] = s + 1e-6f;
    }
    for (int e = lane; e < KK * KSS; e += 64) {
        int k = e / KSS, m = e % KSS;
        float v = perm_s[w][k][m] / colden_s[w][m];
        perm_s[w][k][m] = v * v;
    }
    if (lane < KSS) {
        float s = 0.0f;
        for (int k = 0; k < KK; ++k) s += perm_s[w][k][lane];
        colden_s[w][lane] = s + 1e-6f;
    }
    for (int e = lane; e < KK * KSS; e += 64) {
        int k = e / KSS, m = e % KSS;
        float v = perm_s[w][k][m] / colden_s[w][m];
        perm_s[w][k][m] = v > 0.1f ? v : 0.0f;
    }

    // ---- feats in registers (wave-local) ----
    float fg[KK], fm[KK];
#pragma unroll
    for (int k = 0; k < KK; ++k)
        fg[k] = feature[(size_t)(b * CIN + lane) * NN + nid_s[w][k]];
    {
        float w0 = mlp_w[lane * 7 + 0], w1 = mlp_w[lane * 7 + 1];
        float w2 = mlp_w[lane * 7 + 2], w3 = mlp_w[lane * 7 + 3];
        float w4 = mlp_w[lane * 7 + 4], w5 = mlp_w[lane * 7 + 5];
        float w6 = mlp_w[lane * 7 + 6];
        float bias = mlp_b[lane];
#pragma unroll
        for (int k = 0; k < KK; ++k) {
            fm[k] = xrep_s[w][0] * w0 + xrep_s[w][1] * w1 + xrep_s[w][2] * w2
                  + xr_s[w][k][0] * w3 + xr_s[w][k][1] * w4 + xr_s[w][k][2] * w5
                  + xd_s[w][k] * w6 + bias;
        }
    }

    // ---- agg rows c=lane, c=64+lane; float4 perm reads (broadcast, free) --
#pragma unroll
    for (int m4 = 0; m4 < KSS / 4; ++m4) {
        float sx = 0.f, sy = 0.f, sz = 0.f, sw = 0.f;
        float tx = 0.f, ty = 0.f, tz = 0.f, tw = 0.f;
#pragma unroll
        for (int k = 0; k < KK; ++k) {
            const float4 pv = *(const float4*)&perm_s[w][k][m4 * 4];
            const float a = fg[k], c = fm[k];
            sx += a * pv.x; sy += a * pv.y; sz += a * pv.z; sw += a * pv.w;
            tx += c * pv.x; ty += c * pv.y; tz += c * pv.z; tw += c * pv.w;
        }
        const int mb = m4 * 4;
        agg_h[w][lane * KSS + mb + 0]         = (_Float16)sx;
        agg_h[w][lane * KSS + mb + 1]         = (_Float16)sy;
        agg_h[w][lane * KSS + mb + 2]         = (_Float16)sz;
        agg_h[w][lane * KSS + mb + 3]         = (_Float16)sw;
        agg_h[w][(CIN + lane) * KSS + mb + 0] = (_Float16)tx;
        agg_h[w][(CIN + lane) * KSS + mb + 1] = (_Float16)ty;
        agg_h[w][(CIN + lane) * KSS + mb + 2] = (_Float16)tz;
        agg_h[w][(CIN + lane) * KSS + mb + 3] = (_Float16)tw;
    }
    __syncthreads();   // BARRIER 1: cross-wave agg_h; perm_s -> red_s handoff

    // ---- cooperative conv on the MATRIX pipe ----
    // wave w: M-tile mt=w&3 (outputs 16mt..16mt+15), K-half kh=w>>2 (40 steps)
    // A[m][k] = conv_w[16mt+m][32t+k] (precomputed frags), B[k][n] = agg[n][32t+k]
    // D: col = lane&15 = point (0..7 valid), row = (lane>>4)*4 + reg
    {
        const int mt = w & 3;
        const int kh = w >> 2;
        f32x4 acc0 = {0.f, 0.f, 0.f, 0.f};
        f32x4 acc1 = {0.f, 0.f, 0.f, 0.f};
        const uint4* ap = aFrag + (size_t)(mt * KT + kh * KH) * 64 + lane;
        const _Float16* bp = &agg_h[lane & 7][(lane >> 4) * 8] + (size_t)kh * KH * 32;
#pragma unroll 4
        for (int t = 0; t < KH; t += 2) {
            uint4 av0 = ap[(size_t)t * 64];
            uint4 av1 = ap[(size_t)(t + 1) * 64];
            f16x8 b0 = *(const f16x8*)(bp + t * 32);
            f16x8 b1 = *(const f16x8*)(bp + (t + 1) * 32);
            acc0 = __builtin_amdgcn_mfma_f32_16x16x32_f16(
                       __builtin_bit_cast(f16x8, av0), b0, acc0, 0, 0, 0);
            acc1 = __builtin_amdgcn_mfma_f32_16x16x32_f16(
                       __builtin_bit_cast(f16x8, av1), b1, acc1, 0, 0, 0);
        }
        acc0 += acc1;
        if ((lane & 15) < PPB) {
            const int p2 = lane & 15;
            const int ob = (mt << 4) + ((lane >> 4) << 2);
            *(f32x4*)&red_s[kh][p2][ob] = acc0;
        }
    }
    __syncthreads();   // BARRIER 2: cross-wave red_s

    // ---- wave w finalizes point w ----
    {
        float acc = conv_b[lane] + red_s[0][w][lane] + red_s[1][w][lane];
        for (int c = 0; c < CIN; ++c)
            acc += fcol_s[w][c] * mowT[c * COUT + lane];
        acc += mob[lane];
        out[(size_t)(b * COUT + lane) * NN + n] = acc;
    }
}

// ---------------------------------------------------------------------------
// BatchNorm split: 512-block reduce into partials, 512-block apply.
// ---------------------------------------------------------------------------
__global__ __launch_bounds__(256) void bn_reduce(
    const float* __restrict__ out, float* __restrict__ part)
{
    const int o = blockIdx.x >> 3;     // channel
    const int s = blockIdx.x & 7;      // batch index
    const float* src = out + (size_t)(s * COUT + o) * NN;
    float a = 0.f, q = 0.f;
    for (int i = threadIdx.x; i < NN; i += 256) {
        float v = src[i];
        a += v; q += v * v;
    }
    __shared__ float s1[256], s2[256];
    s1[threadIdx.x] = a; s2[threadIdx.x] = q;
    __syncthreads();
    for (int st = 128; st > 0; st >>= 1) {
        if (threadIdx.x < st) {
            s1[threadIdx.x] += s1[threadIdx.x + st];
            s2[threadIdx.x] += s2[threadIdx.x + st];
        }
        __syncthreads();
    }
    if (threadIdx.x == 0) {
        part[(o * 8 + s) * 2 + 0] = s1[0];
        part[(o * 8 + s) * 2 + 1] = s2[0];
    }
}

__global__ __launch_bounds__(256) void bn_apply(
    float* __restrict__ out, const float* __restrict__ part,
    const float* __restrict__ gamma, const float* __restrict__ beta)
{
    const int o = blockIdx.x >> 3;
    const int s = blockIdx.x & 7;
    float a = 0.f, q = 0.f;
#pragma unroll
    for (int t = 0; t < 8; ++t) {
        a += part[(o * 8 + t) * 2 + 0];
        q += part[(o * 8 + t) * 2 + 1];
    }
    const float M = (float)(BB * NN);
    const float mean = a / M;
    float var = q / M - mean * mean;
    if (var < 0.f) var = 0.f;
    const float inv = 1.0f / sqrtf(var + 1e-5f);
    const float g = gamma[o] * inv, be = beta[o];
    float* dst = out + (size_t)(s * COUT + o) * NN;
    for (int i = threadIdx.x; i < NN; i += 256) {
        dst[i] = (dst[i] - mean) * g + be;
    }
}

// ---------------------------------------------------------------------------
extern "C" void kernel_launch(void* const* d_in, const int* in_sizes, int n_in,
                              void* d_out, int out_size, void* d_ws, size_t ws_size,
                              hipStream_t stream)
{
    const float* x       = (const float*)d_in[0];
    const float* feature = (const float*)d_in[1];
    const float* kern    = (const float*)d_in[2];
    const float* pad     = (const float*)d_in[3];
    const float* mlp_w   = (const float*)d_in[4];
    const float* mlp_b   = (const float*)d_in[5];
    const float* conv_w  = (const float*)d_in[6];
    const float* conv_b  = (const float*)d_in[7];
    const float* mow     = (const float*)d_in[8];
    const float* mob     = (const float*)d_in[9];
    const float* gamma   = (const float*)d_in[10];
    const float* beta    = (const float*)d_in[11];

    char* wsp = (char*)d_ws;
    uint4* aFrag = (uint4*)wsp;                        // 4*80*64*16 = 327680 B
    float* mowT  = (float*)(wsp + 327680);             //  16384 B
    float* part  = (float*)(wsp + 327680 + 16384);     //   4096 B

    float* out = (float*)d_out;

    prep_kernel<<<(4 * KT * 64 + 255) / 256, 256, 0, stream>>>(conv_w, mow, aFrag, mowT);
    point_kernel<<<BB * NN / PPB, 512, 0, stream>>>(x, feature, kern, pad,
                                                    mlp_w, mlp_b, aFrag, conv_b,
                                                    mowT, mob, out);
    bn_reduce<<<512, 256, 0, stream>>>(out, part);
    bn_apply<<<512, 256, 0, stream>>>(out, part, gamma, beta);
}

// Round 3
// 349.489 us; speedup vs baseline: 1.0184x; 1.0184x over previous
//
#include <hip/hip_runtime.h>
#include <cstddef>

#define BB   8
#define NN   2048
#define CIN  64
#define COUT 64
#define KK   20
#define KSS  20
#define C2   128   // 2*CIN
#define PPB  8                 // points per block (8 waves of 64)
#define NC   24                // fp32 candidate count for knn refine
#define KT   80                // K-steps of 32 in conv (2560/32)
#define KH   40                // K-steps per wave (K split in halves)
#define AGG_LD 2568            // padded agg row (f16): keeps 16B align, bank spread

typedef _Float16 h2t  __attribute__((ext_vector_type(2)));
typedef _Float16 f16x8 __attribute__((ext_vector_type(8)));
typedef float    f32x4 __attribute__((ext_vector_type(4)));

__device__ __forceinline__ unsigned pk2(float a, float b) {
    unsigned short ua = __builtin_bit_cast(unsigned short, (_Float16)a);
    unsigned short ub = __builtin_bit_cast(unsigned short, (_Float16)b);
    return (unsigned)ua | ((unsigned)ub << 16);
}

// ---------------------------------------------------------------------------
// Prep:
//  aFrag[(mt*KT + t)*64 + l] = 8 f16 of conv_w[16mt + (l&15)][32t + (l>>4)*8 ..+7]
//    (exact A-fragment layout for mfma_f32_16x16x32_f16, M-tile mt)
//  mowT[c*64 + o] = mlp_out_w[o][c]
// ---------------------------------------------------------------------------
__global__ __launch_bounds__(256) void prep_kernel(
    const float* __restrict__ cw, const float* __restrict__ mw,
    uint4* __restrict__ aFrag, float* __restrict__ mowT)
{
    int i = blockIdx.x * 256 + threadIdx.x;
    if (i < 4 * KT * 64) {
        int wv = i / (KT * 64);
        int r  = i - wv * (KT * 64);
        int t  = r >> 6, l = r & 63;
        int o  = (wv << 4) + (l & 15);
        int j  = (t << 5) + ((l >> 4) << 3);
        const float* s = cw + (size_t)o * (C2 * KSS) + j;
        uint4 v;
        v.x = pk2(s[0], s[1]);
        v.y = pk2(s[2], s[3]);
        v.z = pk2(s[4], s[5]);
        v.w = pk2(s[6], s[7]);
        aFrag[i] = v;
    }
    if (i < COUT * CIN) {
        int o = i >> 6, c = i & 63;
        mowT[c * COUT + o] = mw[o * CIN + c];
    }
}

// ---------------------------------------------------------------------------
// FUSED kernel, PPB=8 / 512 threads. Wave-local phases barrier-free; 2
// barriers total.
// launch_bounds(512, 2): round 2 used (512,4) and the allocator capped at
// 64 arch VGPRs -> 440 MB of scratch spill traffic (WRITE_SIZE 8->258 MB),
// kernel became spill-BW-bound. (512,2) gives the allocator >=128 regs
// under either waves/EU or blocks/CU semantics; demand is ~90 (round-1
// measured 84), so no spill, and 2 blocks/CU (16 waves) still fit both
// the 128-reg step and 2x59.9 KB LDS.
// Conv: M-tile mt = w&3, K-half kh = w>>2, 40 MFMA/wave, 8 valid B columns.
// ---------------------------------------------------------------------------
__global__ __launch_bounds__(512, 2) void point_kernel(
    const float* __restrict__ x,
    const float* __restrict__ feature,
    const float* __restrict__ kern,
    const float* __restrict__ pad,
    const float* __restrict__ mlp_w,
    const float* __restrict__ mlp_b,
    const uint4* __restrict__ aFrag,
    const float* __restrict__ conv_b,
    const float* __restrict__ mowT,
    const float* __restrict__ mob,
    float* __restrict__ out)
{
    __shared__ __align__(16) _Float16 agg_h[PPB][AGG_LD];    // 41088 B
    __shared__ __align__(16) float u_s[PPB * KK * KSS];      // 12800 B (perm|red)
    __shared__ float xr_s[PPB][KK][3];
    __shared__ float xd_s[PPB][KK];
    __shared__ float xrep_s[PPB][3];
    __shared__ float colden_s[PPB][KSS];
    __shared__ float fcol_s[PPB][CIN];
    __shared__ int   nid_s[PPB][KK];

    float (*perm_s)[KK][KSS] = (float (*)[KK][KSS])u_s;
    float (*red_s)[PPB][COUT] = (float (*)[PPB][COUT])u_s;  // [2][8][64] post-B1

    const int tid  = threadIdx.x;
    const int w    = tid >> 6;
    const int lane = tid & 63;
    const int p    = blockIdx.x * PPB + w;
    const int b    = p >> 11;
    const int n    = p & (NN - 1);

    const float* xb0 = x + (size_t)(b * 3 + 0) * NN;
    const float* xb1 = x + (size_t)(b * 3 + 1) * NN;
    const float* xb2 = x + (size_t)(b * 3 + 2) * NN;

    // ================= phase 0: KNN (wave-local, verified v3) =============
    {
        const unsigned long long SENT = 0xFFFFFFFFFFFFFFFFull;
        const float qx = xb0[n], qy = xb1[n], qz = xb2[n];

        float d2r[32];
#pragma unroll
        for (int j = 0; j < 32; ++j) {
            int m = lane + 64 * j;
            float dx = xb0[m] - qx;
            float dy = xb1[m] - qy;
            float dz = xb2[m] - qz;
            d2r[j] = dx * dx + dy * dy + dz * dz;
        }

        unsigned long long c0 = SENT, c1 = SENT, c2 = SENT;
#pragma unroll
        for (int j = 0; j < 32; ++j) {
            unsigned long long pk =
                ((unsigned long long)__float_as_uint(d2r[j]) << 32)
                | (unsigned)(lane + 64 * j);
            if (pk < c0)      { c2 = c1; c1 = c0; c0 = pk; }
            else if (pk < c1) { c2 = c1; c1 = pk; }
            else if (pk < c2) { c2 = pk; }
        }

        unsigned killmask = 0u;
        unsigned long long mypk = SENT;
        for (int k = 0; k < NC; ++k) {
            unsigned long long bp = c0;
#pragma unroll
            for (int off = 32; off > 0; off >>= 1) {
                unsigned long long op_ = __shfl_xor(bp, off);
                if (op_ < bp) bp = op_;
            }
            if (lane == k) mypk = bp;
            if (c0 == bp) {                       // unique owner lane
                killmask |= 1u << ((unsigned)(bp & 0xFFFFFFFFull) >> 6);
                c0 = c1; c1 = c2; c2 = SENT;
                if (c0 == SENT) {                 // rare rescan
#pragma unroll
                    for (int j = 0; j < 32; ++j) {
                        if (!(killmask & (1u << j))) {
                            unsigned long long pk =
                                ((unsigned long long)__float_as_uint(d2r[j]) << 32)
                                | (unsigned)(lane + 64 * j);
                            if (pk < c0)      { c2 = c1; c1 = c0; c0 = pk; }
                            else if (pk < c1) { c2 = c1; c1 = pk; }
                            else if (pk < c2) { c2 = pk; }
                        }
                    }
                }
            }
        }

        double dd = 1e300;
        int ci = 0x7fffffff;
        if (lane < NC) {
            ci = (int)(mypk & 0xFFFFFFFFull);
            double dx = (double)xb0[ci] - (double)qx;
            double dy = (double)xb1[ci] - (double)qy;
            double dz = (double)xb2[ci] - (double)qz;
            dd = dx * dx + dy * dy + dz * dz;
        }
        unsigned long long db = __double_as_longlong(dd);
#pragma unroll
        for (int size = 2; size <= 32; size <<= 1) {
#pragma unroll
            for (int stride = size >> 1; stride > 0; stride >>= 1) {
                unsigned long long odb = __shfl_xor(db, stride);
                int oci = __shfl_xor(ci, stride);
                bool up = ((lane & size) == 0);
                bool takemin = (((lane & stride) == 0) == up);
                bool oless = (odb < db) || (odb == db && oci < ci);
                if (takemin == oless) { db = odb; ci = oci; }
            }
        }
        if (lane < KK) nid_s[w][lane] = ci;     // same-wave producer/consumer
    }

    // ======= per-point pipeline: all wave-local, NO barriers needed =======
    fcol_s[w][lane] = feature[(size_t)(b * CIN + lane) * NN + n];

    if (lane == 0) {
        int m0 = nid_s[w][0];
        xrep_s[w][0] = xb0[m0]; xrep_s[w][1] = xb1[m0]; xrep_s[w][2] = xb2[m0];
    }
    if (lane < KK) {
        int m = nid_s[w][lane];
        float rx = xb0[m] - xrep_s[w][0];
        float ry = xb1[m] - xrep_s[w][1];
        float rz = xb2[m] - xrep_s[w][2];
        xr_s[w][lane][0] = rx; xr_s[w][lane][1] = ry; xr_s[w][lane][2] = rz;
        xd_s[w][lane] = sqrtf(rx * rx + ry * ry + rz * rz + 1e-12f);
    }

    // ---- perm: relu -> colnorm -> square -> colnorm -> >0.1 (wave-local) --
    for (int e = lane; e < KK * KSS; e += 64) {
        int k = e / KSS, m = e % KSS;
        float v = xr_s[w][k][0] * kern[0 * KSS + m]
                + xr_s[w][k][1] * kern[1 * KSS + m]
                + xr_s[w][k][2] * kern[2 * KSS + m]
                + pad[k * KSS + m];
        perm_s[w][k][m] = v > 0.0f ? v : 0.0f;
    }
    if (lane < KSS) {
        float s = 0.0f;
        for (int k = 0; k < KK; ++k) s += perm_s[w][k][lane];
        colden_s[w][lane] = s + 1e-6f;
    }
    for (int e = lane; e < KK * KSS; e += 64) {
        int k = e / KSS, m = e % KSS;
        float v = perm_s[w][k][m] / colden_s[w][m];
        perm_s[w][k][m] = v * v;
    }
    if (lane < KSS) {
        float s = 0.0f;
        for (int k = 0; k < KK; ++k) s += perm_s[w][k][lane];
        colden_s[w][lane] = s + 1e-6f;
    }
    for (int e = lane; e < KK * KSS; e += 64) {
        int k = e / KSS, m = e % KSS;
        float v = perm_s[w][k][m] / colden_s[w][m];
        perm_s[w][k][m] = v > 0.1f ? v : 0.0f;
    }

    // ---- feats in registers (wave-local) ----
    float fg[KK], fm[KK];
#pragma unroll
    for (int k = 0; k < KK; ++k)
        fg[k] = feature[(size_t)(b * CIN + lane) * NN + nid_s[w][k]];
    {
        float w0 = mlp_w[lane * 7 + 0], w1 = mlp_w[lane * 7 + 1];
        float w2 = mlp_w[lane * 7 + 2], w3 = mlp_w[lane * 7 + 3];
        float w4 = mlp_w[lane * 7 + 4], w5 = mlp_w[lane * 7 + 5];
        float w6 = mlp_w[lane * 7 + 6];
        float bias = mlp_b[lane];
#pragma unroll
        for (int k = 0; k < KK; ++k) {
            fm[k] = xrep_s[w][0] * w0 + xrep_s[w][1] * w1 + xrep_s[w][2] * w2
                  + xr_s[w][k][0] * w3 + xr_s[w][k][1] * w4 + xr_s[w][k][2] * w5
                  + xd_s[w][k] * w6 + bias;
        }
    }

    // ---- agg rows c=lane, c=64+lane; float4 perm reads (broadcast, free) --
#pragma unroll
    for (int m4 = 0; m4 < KSS / 4; ++m4) {
        float sx = 0.f, sy = 0.f, sz = 0.f, sw = 0.f;
        float tx = 0.f, ty = 0.f, tz = 0.f, tw = 0.f;
#pragma unroll
        for (int k = 0; k < KK; ++k) {
            const float4 pv = *(const float4*)&perm_s[w][k][m4 * 4];
            const float a = fg[k], c = fm[k];
            sx += a * pv.x; sy += a * pv.y; sz += a * pv.z; sw += a * pv.w;
            tx += c * pv.x; ty += c * pv.y; tz += c * pv.z; tw += c * pv.w;
        }
        const int mb = m4 * 4;
        agg_h[w][lane * KSS + mb + 0]         = (_Float16)sx;
        agg_h[w][lane * KSS + mb + 1]         = (_Float16)sy;
        agg_h[w][lane * KSS + mb + 2]         = (_Float16)sz;
        agg_h[w][lane * KSS + mb + 3]         = (_Float16)sw;
        agg_h[w][(CIN + lane) * KSS + mb + 0] = (_Float16)tx;
        agg_h[w][(CIN + lane) * KSS + mb + 1] = (_Float16)ty;
        agg_h[w][(CIN + lane) * KSS + mb + 2] = (_Float16)tz;
        agg_h[w][(CIN + lane) * KSS + mb + 3] = (_Float16)tw;
    }
    __syncthreads();   // BARRIER 1: cross-wave agg_h; perm_s -> red_s handoff

    // ---- cooperative conv on the MATRIX pipe ----
    // wave w: M-tile mt=w&3 (outputs 16mt..16mt+15), K-half kh=w>>2 (40 steps)
    // A[m][k] = conv_w[16mt+m][32t+k] (precomputed frags), B[k][n] = agg[n][32t+k]
    // D: col = lane&15 = point (0..7 valid), row = (lane>>4)*4 + reg
    {
        const int mt = w & 3;
        const int kh = w >> 2;
        f32x4 acc0 = {0.f, 0.f, 0.f, 0.f};
        f32x4 acc1 = {0.f, 0.f, 0.f, 0.f};
        const uint4* ap = aFrag + (size_t)(mt * KT + kh * KH) * 64 + lane;
        const _Float16* bp = &agg_h[lane & 7][(lane >> 4) * 8] + (size_t)kh * KH * 32;
#pragma unroll 4
        for (int t = 0; t < KH; t += 2) {
            uint4 av0 = ap[(size_t)t * 64];
            uint4 av1 = ap[(size_t)(t + 1) * 64];
            f16x8 b0 = *(const f16x8*)(bp + t * 32);
            f16x8 b1 = *(const f16x8*)(bp + (t + 1) * 32);
            acc0 = __builtin_amdgcn_mfma_f32_16x16x32_f16(
                       __builtin_bit_cast(f16x8, av0), b0, acc0, 0, 0, 0);
            acc1 = __builtin_amdgcn_mfma_f32_16x16x32_f16(
                       __builtin_bit_cast(f16x8, av1), b1, acc1, 0, 0, 0);
        }
        acc0 += acc1;
        if ((lane & 15) < PPB) {
            const int p2 = lane & 15;
            const int ob = (mt << 4) + ((lane >> 4) << 2);
            *(f32x4*)&red_s[kh][p2][ob] = acc0;
        }
    }
    __syncthreads();   // BARRIER 2: cross-wave red_s

    // ---- wave w finalizes point w ----
    {
        float acc = conv_b[lane] + red_s[0][w][lane] + red_s[1][w][lane];
        for (int c = 0; c < CIN; ++c)
            acc += fcol_s[w][c] * mowT[c * COUT + lane];
        acc += mob[lane];
        out[(size_t)(b * COUT + lane) * NN + n] = acc;
    }
}

// ---------------------------------------------------------------------------
// BatchNorm split: 512-block reduce into partials, 512-block apply.
// ---------------------------------------------------------------------------
__global__ __launch_bounds__(256) void bn_reduce(
    const float* __restrict__ out, float* __restrict__ part)
{
    const int o = blockIdx.x >> 3;     // channel
    const int s = blockIdx.x & 7;      // batch index
    const float* src = out + (size_t)(s * COUT + o) * NN;
    float a = 0.f, q = 0.f;
    for (int i = threadIdx.x; i < NN; i += 256) {
        float v = src[i];
        a += v; q += v * v;
    }
    __shared__ float s1[256], s2[256];
    s1[threadIdx.x] = a; s2[threadIdx.x] = q;
    __syncthreads();
    for (int st = 128; st > 0; st >>= 1) {
        if (threadIdx.x < st) {
            s1[threadIdx.x] += s1[threadIdx.x + st];
            s2[threadIdx.x] += s2[threadIdx.x + st];
        }
        __syncthreads();
    }
    if (threadIdx.x == 0) {
        part[(o * 8 + s) * 2 + 0] = s1[0];
        part[(o * 8 + s) * 2 + 1] = s2[0];
    }
}

__global__ __launch_bounds__(256) void bn_apply(
    float* __restrict__ out, const float* __restrict__ part,
    const float* __restrict__ gamma, const float* __restrict__ beta)
{
    const int o = blockIdx.x >> 3;
    const int s = blockIdx.x & 7;
    float a = 0.f, q = 0.f;
#pragma unroll
    for (int t = 0; t < 8; ++t) {
        a += part[(o * 8 + t) * 2 + 0];
        q += part[(o * 8 + t) * 2 + 1];
    }
    const float M = (float)(BB * NN);
    const float mean = a / M;
    float var = q / M - mean * mean;
    if (var < 0.f) var = 0.f;
    const float inv = 1.0f / sqrtf(var + 1e-5f);
    const float g = gamma[o] * inv, be = beta[o];
    float* dst = out + (size_t)(s * COUT + o) * NN;
    for (int i = threadIdx.x; i < NN; i += 256) {
        dst[i] = (dst[i] - mean) * g + be;
    }
}

// ---------------------------------------------------------------------------
extern "C" void kernel_launch(void* const* d_in, const int* in_sizes, int n_in,
                              void* d_out, int out_size, void* d_ws, size_t ws_size,
                              hipStream_t stream)
{
    const float* x       = (const float*)d_in[0];
    const float* feature = (const float*)d_in[1];
    const float* kern    = (const float*)d_in[2];
    const float* pad     = (const float*)d_in[3];
    const float* mlp_w   = (const float*)d_in[4];
    const float* mlp_b   = (const float*)d_in[5];
    const float* conv_w  = (const float*)d_in[6];
    const float* conv_b  = (const float*)d_in[7];
    const float* mow     = (const float*)d_in[8];
    const float* mob     = (const float*)d_in[9];
    const float* gamma   = (const float*)d_in[10];
    const float* beta    = (const float*)d_in[11];

    char* wsp = (char*)d_ws;
    uint4* aFrag = (uint4*)wsp;                        // 4*80*64*16 = 327680 B
    float* mowT  = (float*)(wsp + 327680);             //  16384 B
    float* part  = (float*)(wsp + 327680 + 16384);     //   4096 B

    float* out = (float*)d_out;

    prep_kernel<<<(4 * KT * 64 + 255) / 256, 256, 0, stream>>>(conv_w, mow, aFrag, mowT);
    point_kernel<<<BB * NN / PPB, 512, 0, stream>>>(x, feature, kern, pad,
                                                    mlp_w, mlp_b, aFrag, conv_b,
                                                    mowT, mob, out);
    bn_reduce<<<512, 256, 0, stream>>>(out, part);
    bn_apply<<<512, 256, 0, stream>>>(out, part, gamma, beta);
}

// Round 4
// 322.590 us; speedup vs baseline: 1.1033x; 1.0834x over previous
//
#include <hip/hip_runtime.h>
#include <cstddef>

#define BB   8
#define NN   2048
#define CIN  64
#define COUT 64
#define KK   20
#define KSS  20
#define C2   128   // 2*CIN
#define PPB  4                 // points per block (4 waves of 64) — round-1 best
#define NC   24                // fp32 candidate count for knn refine
#define KT   80                // K-steps of 32 in conv (2560/32)
#define AGG_LD 2576            // padded agg row (f16), round-1 value

typedef _Float16 h2t  __attribute__((ext_vector_type(2)));
typedef _Float16 f16x8 __attribute__((ext_vector_type(8)));
typedef float    f32x4 __attribute__((ext_vector_type(4)));

__device__ __forceinline__ unsigned pk2(float a, float b) {
    unsigned short ua = __builtin_bit_cast(unsigned short, (_Float16)a);
    unsigned short ub = __builtin_bit_cast(unsigned short, (_Float16)b);
    return (unsigned)ua | ((unsigned)ub << 16);
}

// ---------------------------------------------------------------------------
// Prep:
//  aFrag[(mt*KT + t)*64 + l] = 8 f16 of conv_w[16mt + (l&15)][32t + (l>>4)*8 ..+7]
//  mowT[c*64 + o] = mlp_out_w[o][c]
// ---------------------------------------------------------------------------
__global__ __launch_bounds__(256) void prep_kernel(
    const float* __restrict__ cw, const float* __restrict__ mw,
    uint4* __restrict__ aFrag, float* __restrict__ mowT)
{
    int i = blockIdx.x * 256 + threadIdx.x;
    if (i < 4 * KT * 64) {
        int wv = i / (KT * 64);
        int r  = i - wv * (KT * 64);
        int t  = r >> 6, l = r & 63;
        int o  = (wv << 4) + (l & 15);
        int j  = (t << 5) + ((l >> 4) << 3);
        const float* s = cw + (size_t)o * (C2 * KSS) + j;
        uint4 v;
        v.x = pk2(s[0], s[1]);
        v.y = pk2(s[2], s[3]);
        v.z = pk2(s[4], s[5]);
        v.w = pk2(s[6], s[7]);
        aFrag[i] = v;
    }
    if (i < COUT * CIN) {
        int o = i >> 6, c = i & 63;
        mowT[c * COUT + o] = mw[o * CIN + c];
    }
}

// ---------------------------------------------------------------------------
// KNN kernel — the verified wave-local selection, SPLIT OUT so its serial
// shuffle chain runs at high occupancy (no LDS, ~80 VGPR -> 4 waves/SIMD).
// One wave per point; writes sorted neighbor ids to nid[p*KK + k].
// ---------------------------------------------------------------------------
__global__ __launch_bounds__(256, 4) void knn_kernel(
    const float* __restrict__ x, int* __restrict__ nid)
{
    const int tid  = threadIdx.x;
    const int w    = tid >> 6;
    const int lane = tid & 63;
    const int p    = blockIdx.x * 4 + w;
    const int b    = p >> 11;
    const int n    = p & (NN - 1);

    const float* xb0 = x + (size_t)(b * 3 + 0) * NN;
    const float* xb1 = x + (size_t)(b * 3 + 1) * NN;
    const float* xb2 = x + (size_t)(b * 3 + 2) * NN;

    const unsigned long long SENT = 0xFFFFFFFFFFFFFFFFull;
    const float qx = xb0[n], qy = xb1[n], qz = xb2[n];

    float d2r[32];
#pragma unroll
    for (int j = 0; j < 32; ++j) {
        int m = lane + 64 * j;
        float dx = xb0[m] - qx;
        float dy = xb1[m] - qy;
        float dz = xb2[m] - qz;
        d2r[j] = dx * dx + dy * dy + dz * dz;
    }

    unsigned long long c0 = SENT, c1 = SENT, c2 = SENT;
#pragma unroll
    for (int j = 0; j < 32; ++j) {
        unsigned long long pk =
            ((unsigned long long)__float_as_uint(d2r[j]) << 32)
            | (unsigned)(lane + 64 * j);
        if (pk < c0)      { c2 = c1; c1 = c0; c0 = pk; }
        else if (pk < c1) { c2 = c1; c1 = pk; }
        else if (pk < c2) { c2 = pk; }
    }

    unsigned killmask = 0u;
    unsigned long long mypk = SENT;
    for (int k = 0; k < NC; ++k) {
        unsigned long long bp = c0;
#pragma unroll
        for (int off = 32; off > 0; off >>= 1) {
            unsigned long long op_ = __shfl_xor(bp, off);
            if (op_ < bp) bp = op_;
        }
        if (lane == k) mypk = bp;
        if (c0 == bp) {                       // unique owner lane
            killmask |= 1u << ((unsigned)(bp & 0xFFFFFFFFull) >> 6);
            c0 = c1; c1 = c2; c2 = SENT;
            if (c0 == SENT) {                 // rare rescan
#pragma unroll
                for (int j = 0; j < 32; ++j) {
                    if (!(killmask & (1u << j))) {
                        unsigned long long pk =
                            ((unsigned long long)__float_as_uint(d2r[j]) << 32)
                            | (unsigned)(lane + 64 * j);
                        if (pk < c0)      { c2 = c1; c1 = c0; c0 = pk; }
                        else if (pk < c1) { c2 = c1; c1 = pk; }
                        else if (pk < c2) { c2 = pk; }
                    }
                }
            }
        }
    }

    double dd = 1e300;
    int ci = 0x7fffffff;
    if (lane < NC) {
        ci = (int)(mypk & 0xFFFFFFFFull);
        double dx = (double)xb0[ci] - (double)qx;
        double dy = (double)xb1[ci] - (double)qy;
        double dz = (double)xb2[ci] - (double)qz;
        dd = dx * dx + dy * dy + dz * dz;
    }
    unsigned long long db = __double_as_longlong(dd);
#pragma unroll
    for (int size = 2; size <= 32; size <<= 1) {
#pragma unroll
        for (int stride = size >> 1; stride > 0; stride >>= 1) {
            unsigned long long odb = __shfl_xor(db, stride);
            int oci = __shfl_xor(ci, stride);
            bool up = ((lane & size) == 0);
            bool takemin = (((lane & stride) == 0) == up);
            bool oless = (odb < db) || (odb == db && oci < ci);
            if (takemin == oless) { db = odb; ci = oci; }
        }
    }
    if (lane < KK) nid[(size_t)p * KK + lane] = ci;
}

// ---------------------------------------------------------------------------
// FUSED kernel (round-1 best structure, KNN removed). PPB=4 / 256 threads,
// 2 barriers. launch_bounds(256,3): proven no-spill. Reads nid from global.
// ---------------------------------------------------------------------------
__global__ __launch_bounds__(256, 3) void point_kernel(
    const float* __restrict__ x,
    const float* __restrict__ feature,
    const float* __restrict__ kern,
    const float* __restrict__ pad,
    const float* __restrict__ mlp_w,
    const float* __restrict__ mlp_b,
    const uint4* __restrict__ aFrag,
    const float* __restrict__ conv_b,
    const float* __restrict__ mowT,
    const float* __restrict__ mob,
    const int* __restrict__ nid,
    float* __restrict__ out)
{
    __shared__ __align__(16) _Float16 agg_h[PPB][AGG_LD];    // 20608 B
    __shared__ __align__(16) float u_s[PPB * KK * KSS];      // 6400 B (perm|red2)
    __shared__ float xr_s[PPB][KK][3];
    __shared__ float xd_s[PPB][KK];
    __shared__ float xrep_s[PPB][3];
    __shared__ float colden_s[PPB][KSS];
    __shared__ float fcol_s[PPB][CIN];
    __shared__ int   nid_s[PPB][KK];

    float (*perm_s)[KK][KSS] = (float (*)[KK][KSS])u_s;
    float (*red2)[COUT]      = (float (*)[COUT])u_s;   // aliased post-barrier1

    const int tid  = threadIdx.x;
    const int w    = tid >> 6;
    const int lane = tid & 63;
    const int p    = blockIdx.x * PPB + w;
    const int b    = p >> 11;
    const int n    = p & (NN - 1);

    const float* xb0 = x + (size_t)(b * 3 + 0) * NN;
    const float* xb1 = x + (size_t)(b * 3 + 1) * NN;
    const float* xb2 = x + (size_t)(b * 3 + 2) * NN;

    // ---- neighbor ids from the KNN kernel (wave-local LDS stage) ----
    if (lane < KK) nid_s[w][lane] = nid[(size_t)p * KK + lane];

    // ======= per-point pipeline: all wave-local, NO barriers needed =======
    fcol_s[w][lane] = feature[(size_t)(b * CIN + lane) * NN + n];

    if (lane == 0) {
        int m0 = nid_s[w][0];
        xrep_s[w][0] = xb0[m0]; xrep_s[w][1] = xb1[m0]; xrep_s[w][2] = xb2[m0];
    }
    if (lane < KK) {
        int m = nid_s[w][lane];
        float rx = xb0[m] - xrep_s[w][0];
        float ry = xb1[m] - xrep_s[w][1];
        float rz = xb2[m] - xrep_s[w][2];
        xr_s[w][lane][0] = rx; xr_s[w][lane][1] = ry; xr_s[w][lane][2] = rz;
        xd_s[w][lane] = sqrtf(rx * rx + ry * ry + rz * rz + 1e-12f);
    }

    // ---- perm: relu -> colnorm -> square -> colnorm -> >0.1 (wave-local) --
    for (int e = lane; e < KK * KSS; e += 64) {
        int k = e / KSS, m = e % KSS;
        float v = xr_s[w][k][0] * kern[0 * KSS + m]
                + xr_s[w][k][1] * kern[1 * KSS + m]
                + xr_s[w][k][2] * kern[2 * KSS + m]
                + pad[k * KSS + m];
        perm_s[w][k][m] = v > 0.0f ? v : 0.0f;
    }
    if (lane < KSS) {
        float s = 0.0f;
        for (int k = 0; k < KK; ++k) s += perm_s[w][k][lane];
        colden_s[w][lane] = s + 1e-6f;
    }
    for (int e = lane; e < KK * KSS; e += 64) {
        int k = e / KSS, m = e % KSS;
        float v = perm_s[w][k][m] / colden_s[w][m];
        perm_s[w][k][m] = v * v;
    }
    if (lane < KSS) {
        float s = 0.0f;
        for (int k = 0; k < KK; ++k) s += perm_s[w][k][lane];
        colden_s[w][lane] = s + 1e-6f;
    }
    for (int e = lane; e < KK * KSS; e += 64) {
        int k = e / KSS, m = e % KSS;
        float v = perm_s[w][k][m] / colden_s[w][m];
        perm_s[w][k][m] = v > 0.1f ? v : 0.0f;
    }

    // ---- feats in registers (wave-local) ----
    float fg[KK], fm[KK];
#pragma unroll
    for (int k = 0; k < KK; ++k)
        fg[k] = feature[(size_t)(b * CIN + lane) * NN + nid_s[w][k]];
    {
        float w0 = mlp_w[lane * 7 + 0], w1 = mlp_w[lane * 7 + 1];
        float w2 = mlp_w[lane * 7 + 2], w3 = mlp_w[lane * 7 + 3];
        float w4 = mlp_w[lane * 7 + 4], w5 = mlp_w[lane * 7 + 5];
        float w6 = mlp_w[lane * 7 + 6];
        float bias = mlp_b[lane];
#pragma unroll
        for (int k = 0; k < KK; ++k) {
            fm[k] = xrep_s[w][0] * w0 + xrep_s[w][1] * w1 + xrep_s[w][2] * w2
                  + xr_s[w][k][0] * w3 + xr_s[w][k][1] * w4 + xr_s[w][k][2] * w5
                  + xd_s[w][k] * w6 + bias;
        }
    }

    // ---- agg rows c=lane, c=64+lane; float4 perm reads (broadcast, free) --
#pragma unroll
    for (int m4 = 0; m4 < KSS / 4; ++m4) {
        float sx = 0.f, sy = 0.f, sz = 0.f, sw = 0.f;
        float tx = 0.f, ty = 0.f, tz = 0.f, tw = 0.f;
#pragma unroll
        for (int k = 0; k < KK; ++k) {
            const float4 pv = *(const float4*)&perm_s[w][k][m4 * 4];
            const float a = fg[k], c = fm[k];
            sx += a * pv.x; sy += a * pv.y; sz += a * pv.z; sw += a * pv.w;
            tx += c * pv.x; ty += c * pv.y; tz += c * pv.z; tw += c * pv.w;
        }
        const int mb = m4 * 4;
        agg_h[w][lane * KSS + mb + 0]         = (_Float16)sx;
        agg_h[w][lane * KSS + mb + 1]         = (_Float16)sy;
        agg_h[w][lane * KSS + mb + 2]         = (_Float16)sz;
        agg_h[w][lane * KSS + mb + 3]         = (_Float16)sw;
        agg_h[w][(CIN + lane) * KSS + mb + 0] = (_Float16)tx;
        agg_h[w][(CIN + lane) * KSS + mb + 1] = (_Float16)ty;
        agg_h[w][(CIN + lane) * KSS + mb + 2] = (_Float16)tz;
        agg_h[w][(CIN + lane) * KSS + mb + 3] = (_Float16)tw;
    }
    __syncthreads();   // BARRIER 1: cross-wave agg_h; perm_s -> red2 handoff

    // ---- cooperative conv on the MATRIX pipe: wave w = outputs 16w..16w+15
    // A[m][k] = conv_w[16w+m][32t+k] (precomputed frags), B[k][n] = agg[n][32t+k]
    // D: col = lane&15 = point (0..3 valid), row = (lane>>4)*4 + reg
    {
        f32x4 acc0 = {0.f, 0.f, 0.f, 0.f};
        f32x4 acc1 = {0.f, 0.f, 0.f, 0.f};
        const uint4* ap = aFrag + (size_t)(w * KT) * 64 + lane;
        const _Float16* bp = &agg_h[lane & 3][(lane >> 4) * 8];
#pragma unroll 4
        for (int t = 0; t < KT; t += 2) {
            uint4 av0 = ap[(size_t)t * 64];
            uint4 av1 = ap[(size_t)(t + 1) * 64];
            f16x8 b0 = *(const f16x8*)(bp + t * 32);
            f16x8 b1 = *(const f16x8*)(bp + (t + 1) * 32);
            acc0 = __builtin_amdgcn_mfma_f32_16x16x32_f16(
                       __builtin_bit_cast(f16x8, av0), b0, acc0, 0, 0, 0);
            acc1 = __builtin_amdgcn_mfma_f32_16x16x32_f16(
                       __builtin_bit_cast(f16x8, av1), b1, acc1, 0, 0, 0);
        }
        acc0 += acc1;
        if ((lane & 15) < 4) {
            const int p2 = lane & 15;
            const int ob = (w << 4) + ((lane >> 4) << 2);
            *(f32x4*)&red2[p2][ob] = acc0;
        }
    }
    __syncthreads();   // BARRIER 2: cross-wave red2

    // ---- wave w finalizes point w ----
    {
        float acc = conv_b[lane] + red2[w][lane];
        for (int c = 0; c < CIN; ++c)
            acc += fcol_s[w][c] * mowT[c * COUT + lane];
        acc += mob[lane];
        out[(size_t)(b * COUT + lane) * NN + n] = acc;
    }
}

// ---------------------------------------------------------------------------
// BatchNorm split: 512-block reduce into partials, 512-block apply.
// ---------------------------------------------------------------------------
__global__ __launch_bounds__(256) void bn_reduce(
    const float* __restrict__ out, float* __restrict__ part)
{
    const int o = blockIdx.x >> 3;     // channel
    const int s = blockIdx.x & 7;      // batch index
    const float* src = out + (size_t)(s * COUT + o) * NN;
    float a = 0.f, q = 0.f;
    for (int i = threadIdx.x; i < NN; i += 256) {
        float v = src[i];
        a += v; q += v * v;
    }
    __shared__ float s1[256], s2[256];
    s1[threadIdx.x] = a; s2[threadIdx.x] = q;
    __syncthreads();
    for (int st = 128; st > 0; st >>= 1) {
        if (threadIdx.x < st) {
            s1[threadIdx.x] += s1[threadIdx.x + st];
            s2[threadIdx.x] += s2[threadIdx.x + st];
        }
        __syncthreads();
    }
    if (threadIdx.x == 0) {
        part[(o * 8 + s) * 2 + 0] = s1[0];
        part[(o * 8 + s) * 2 + 1] = s2[0];
    }
}

__global__ __launch_bounds__(256) void bn_apply(
    float* __restrict__ out, const float* __restrict__ part,
    const float* __restrict__ gamma, const float* __restrict__ beta)
{
    const int o = blockIdx.x >> 3;
    const int s = blockIdx.x & 7;
    float a = 0.f, q = 0.f;
#pragma unroll
    for (int t = 0; t < 8; ++t) {
        a += part[(o * 8 + t) * 2 + 0];
        q += part[(o * 8 + t) * 2 + 1];
    }
    const float M = (float)(BB * NN);
    const float mean = a / M;
    float var = q / M - mean * mean;
    if (var < 0.f) var = 0.f;
    const float inv = 1.0f / sqrtf(var + 1e-5f);
    const float g = gamma[o] * inv, be = beta[o];
    float* dst = out + (size_t)(s * COUT + o) * NN;
    for (int i = threadIdx.x; i < NN; i += 256) {
        dst[i] = (dst[i] - mean) * g + be;
    }
}

// ---------------------------------------------------------------------------
extern "C" void kernel_launch(void* const* d_in, const int* in_sizes, int n_in,
                              void* d_out, int out_size, void* d_ws, size_t ws_size,
                              hipStream_t stream)
{
    const float* x       = (const float*)d_in[0];
    const float* feature = (const float*)d_in[1];
    const float* kern    = (const float*)d_in[2];
    const float* pad     = (const float*)d_in[3];
    const float* mlp_w   = (const float*)d_in[4];
    const float* mlp_b   = (const float*)d_in[5];
    const float* conv_w  = (const float*)d_in[6];
    const float* conv_b  = (const float*)d_in[7];
    const float* mow     = (const float*)d_in[8];
    const float* mob     = (const float*)d_in[9];
    const float* gamma   = (const float*)d_in[10];
    const float* beta    = (const float*)d_in[11];

    char* wsp = (char*)d_ws;
    uint4* aFrag = (uint4*)wsp;                        // 4*80*64*16 = 327680 B
    float* mowT  = (float*)(wsp + 327680);             //  16384 B
    float* part  = (float*)(wsp + 327680 + 16384);     //   4096 B
    int*   nid   = (int*)(wsp + 327680 + 16384 + 4096);// 16384*20*4 = 1310720 B

    float* out = (float*)d_out;

    prep_kernel<<<(4 * KT * 64 + 255) / 256, 256, 0, stream>>>(conv_w, mow, aFrag, mowT);
    knn_kernel<<<BB * NN / 4, 256, 0, stream>>>(x, nid);
    point_kernel<<<BB * NN / PPB, 256, 0, stream>>>(x, feature, kern, pad,
                                                    mlp_w, mlp_b, aFrag, conv_b,
                                                    mowT, mob, nid, out);
    bn_reduce<<<512, 256, 0, stream>>>(out, part);
    bn_apply<<<512, 256, 0, stream>>>(out, part, gamma, beta);
}

// Round 6
// 249.803 us; speedup vs baseline: 1.4248x; 1.2914x over previous
//
#include <hip/hip_runtime.h>
#include <cstddef>

#define BB   8
#define NN   2048
#define CIN  64
#define COUT 64
#define KK   20
#define KSS  20
#define C2   128   // 2*CIN
#define PPB  4                 // points per block (4 waves of 64)
#define NC   24                // fp32 candidate count for knn refine
#define KT   80                // K-steps of 32 in conv (2560/32)
#define AGG_LD 2576            // padded agg row (f16)

typedef _Float16 h2t  __attribute__((ext_vector_type(2)));
typedef _Float16 f16x8 __attribute__((ext_vector_type(8)));
typedef float    f32x4 __attribute__((ext_vector_type(4)));

__device__ __forceinline__ unsigned pk2(float a, float b) {
    unsigned short ua = __builtin_bit_cast(unsigned short, (_Float16)a);
    unsigned short ub = __builtin_bit_cast(unsigned short, (_Float16)b);
    return (unsigned)ua | ((unsigned)ub << 16);
}

// Wave64 min-reduce on the VALU via DPP (no LDS pipe).
// ROUND-6 FIX: row_shr (0x111..0x118), NOT row_shl — row_shr accumulates the
// row-min into the HIGH lane of each 16-row (lane 15/31/47/63), which is what
// row_bcast:15 / row_bcast:31 / readlane(63) require. Round 5 used row_shl
// (min into lane 0) -> bcast propagated unreduced values -> wrong KNN.
// bound_ctrl=false keeps old value on invalid lanes; min is idempotent.
__device__ __forceinline__ unsigned wave_min_u32(unsigned v) {
    unsigned x = v, t;
    t = (unsigned)__builtin_amdgcn_update_dpp((int)x, (int)x, 0x111, 0xf, 0xf, false); // row_shr:1
    x = (t < x) ? t : x;
    t = (unsigned)__builtin_amdgcn_update_dpp((int)x, (int)x, 0x112, 0xf, 0xf, false); // row_shr:2
    x = (t < x) ? t : x;
    t = (unsigned)__builtin_amdgcn_update_dpp((int)x, (int)x, 0x114, 0xf, 0xf, false); // row_shr:4
    x = (t < x) ? t : x;
    t = (unsigned)__builtin_amdgcn_update_dpp((int)x, (int)x, 0x118, 0xf, 0xf, false); // row_shr:8
    x = (t < x) ? t : x;
    t = (unsigned)__builtin_amdgcn_update_dpp((int)x, (int)x, 0x142, 0xf, 0xf, false); // row_bcast:15
    x = (t < x) ? t : x;
    t = (unsigned)__builtin_amdgcn_update_dpp((int)x, (int)x, 0x143, 0xf, 0xf, false); // row_bcast:31
    x = (t < x) ? t : x;
    return (unsigned)__builtin_amdgcn_readlane((int)x, 63);
}

// ---------------------------------------------------------------------------
// Prep: aFrag = MFMA A-fragments of conv_w (f16); mowT = mlp_out_w transposed
// ---------------------------------------------------------------------------
__global__ __launch_bounds__(256) void prep_kernel(
    const float* __restrict__ cw, const float* __restrict__ mw,
    uint4* __restrict__ aFrag, float* __restrict__ mowT)
{
    int i = blockIdx.x * 256 + threadIdx.x;
    if (i < 4 * KT * 64) {
        int wv = i / (KT * 64);
        int r  = i - wv * (KT * 64);
        int t  = r >> 6, l = r & 63;
        int o  = (wv << 4) + (l & 15);
        int j  = (t << 5) + ((l >> 4) << 3);
        const float* s = cw + (size_t)o * (C2 * KSS) + j;
        uint4 v;
        v.x = pk2(s[0], s[1]);
        v.y = pk2(s[2], s[3]);
        v.z = pk2(s[4], s[5]);
        v.w = pk2(s[6], s[7]);
        aFrag[i] = v;
    }
    if (i < COUT * CIN) {
        int o = i >> 6, c = i & 63;
        mowT[c * COUT + o] = mw[o * CIN + c];
    }
}

// ---------------------------------------------------------------------------
// Transpose feature [B][C][N] -> featT [B][N][C] so per-k neighbor gathers in
// point_kernel are coalesced (256 B / 4 lines per wave instead of 64 lines).
// ---------------------------------------------------------------------------
__global__ __launch_bounds__(256) void tr_kernel(
    const float* __restrict__ f, float* __restrict__ ft)
{
    __shared__ float tile[64][65];
    const int bt = blockIdx.x;          // b*32 + ntile
    const int b  = bt >> 5;
    const int n0 = (bt & 31) << 6;
    const int tn  = threadIdx.x & 63;
    const int tc0 = threadIdx.x >> 6;   // 0..3
#pragma unroll
    for (int r = 0; r < 16; ++r) {
        int c = (r << 2) + tc0;
        tile[c][tn] = f[((size_t)(b * CIN + c)) * NN + n0 + tn];
    }
    __syncthreads();
#pragma unroll
    for (int r = 0; r < 16; ++r) {
        int n = (r << 2) + tc0;
        ft[((size_t)b * NN + n0 + n) * CIN + tn] = tile[tn][n];
    }
}

// ---------------------------------------------------------------------------
// KNN kernel — wave-local selection; 24 sequential global-min extractions via
// the (fixed) DPP VALU reduce on (d2bits, then idx among d2-ties). Identical
// lexicographic-min result to the 64-bit butterfly (indices lane-unique).
// ---------------------------------------------------------------------------
__global__ __launch_bounds__(256, 4) void knn_kernel(
    const float* __restrict__ x, int* __restrict__ nid)
{
    const int tid  = threadIdx.x;
    const int w    = tid >> 6;
    const int lane = tid & 63;
    const int p    = blockIdx.x * 4 + w;
    const int b    = p >> 11;
    const int n    = p & (NN - 1);

    const float* xb0 = x + (size_t)(b * 3 + 0) * NN;
    const float* xb1 = x + (size_t)(b * 3 + 1) * NN;
    const float* xb2 = x + (size_t)(b * 3 + 2) * NN;

    const unsigned long long SENT = 0xFFFFFFFFFFFFFFFFull;
    const float qx = xb0[n], qy = xb1[n], qz = xb2[n];

    float d2r[32];
#pragma unroll
    for (int j = 0; j < 32; ++j) {
        int m = lane + 64 * j;
        float dx = xb0[m] - qx;
        float dy = xb1[m] - qy;
        float dz = xb2[m] - qz;
        d2r[j] = dx * dx + dy * dy + dz * dz;
    }

    unsigned long long c0 = SENT, c1 = SENT, c2 = SENT;
#pragma unroll
    for (int j = 0; j < 32; ++j) {
        unsigned long long pk =
            ((unsigned long long)__float_as_uint(d2r[j]) << 32)
            | (unsigned)(lane + 64 * j);
        if (pk < c0)      { c2 = c1; c1 = c0; c0 = pk; }
        else if (pk < c1) { c2 = c1; c1 = pk; }
        else if (pk < c2) { c2 = pk; }
    }

    unsigned killmask = 0u;
    unsigned long long mypk = SENT;
    for (int k = 0; k < NC; ++k) {
        // global lexicographic min of c0 via two 32-bit DPP reduces
        unsigned myd  = (unsigned)(c0 >> 32);
        unsigned dmin = wave_min_u32(myd);
        unsigned idxc = (myd == dmin) ? (unsigned)c0 : 0xFFFFFFFFu;
        unsigned imin = wave_min_u32(idxc);
        unsigned long long bp = ((unsigned long long)dmin << 32) | imin;

        if (lane == k) mypk = bp;
        if (c0 == bp) {                       // unique owner lane
            killmask |= 1u << ((unsigned)(bp & 0xFFFFFFFFull) >> 6);
            c0 = c1; c1 = c2; c2 = SENT;
            if (c0 == SENT) {                 // rare rescan
#pragma unroll
                for (int j = 0; j < 32; ++j) {
                    if (!(killmask & (1u << j))) {
                        unsigned long long pk =
                            ((unsigned long long)__float_as_uint(d2r[j]) << 32)
                            | (unsigned)(lane + 64 * j);
                        if (pk < c0)      { c2 = c1; c1 = c0; c0 = pk; }
                        else if (pk < c1) { c2 = c1; c1 = pk; }
                        else if (pk < c2) { c2 = pk; }
                    }
                }
            }
        }
    }

    double dd = 1e300;
    int ci = 0x7fffffff;
    if (lane < NC) {
        ci = (int)(mypk & 0xFFFFFFFFull);
        double dx = (double)xb0[ci] - (double)qx;
        double dy = (double)xb1[ci] - (double)qy;
        double dz = (double)xb2[ci] - (double)qz;
        dd = dx * dx + dy * dy + dz * dz;
    }
    unsigned long long db = __double_as_longlong(dd);
#pragma unroll
    for (int size = 2; size <= 32; size <<= 1) {
#pragma unroll
        for (int stride = size >> 1; stride > 0; stride >>= 1) {
            unsigned long long odb = __shfl_xor(db, stride);
            int oci = __shfl_xor(ci, stride);
            bool up = ((lane & size) == 0);
            bool takemin = (((lane & stride) == 0) == up);
            bool oless = (odb < db) || (odb == db && oci < ci);
            if (takemin == oless) { db = odb; ci = oci; }
        }
    }
    if (lane < KK) nid[(size_t)p * KK + lane] = ci;
}

// ---------------------------------------------------------------------------
// FUSED kernel (round-4 structure); feature reads via featT [B][N][C].
// ---------------------------------------------------------------------------
__global__ __launch_bounds__(256, 3) void point_kernel(
    const float* __restrict__ x,
    const float* __restrict__ featT,
    const float* __restrict__ kern,
    const float* __restrict__ pad,
    const float* __restrict__ mlp_w,
    const float* __restrict__ mlp_b,
    const uint4* __restrict__ aFrag,
    const float* __restrict__ conv_b,
    const float* __restrict__ mowT,
    const float* __restrict__ mob,
    const int* __restrict__ nid,
    float* __restrict__ out)
{
    __shared__ __align__(16) _Float16 agg_h[PPB][AGG_LD];    // 20608 B
    __shared__ __align__(16) float u_s[PPB * KK * KSS];      // 6400 B (perm|red2)
    __shared__ float xr_s[PPB][KK][3];
    __shared__ float xd_s[PPB][KK];
    __shared__ float xrep_s[PPB][3];
    __shared__ float colden_s[PPB][KSS];
    __shared__ float fcol_s[PPB][CIN];
    __shared__ int   nid_s[PPB][KK];

    float (*perm_s)[KK][KSS] = (float (*)[KK][KSS])u_s;
    float (*red2)[COUT]      = (float (*)[COUT])u_s;   // aliased post-barrier1

    const int tid  = threadIdx.x;
    const int w    = tid >> 6;
    const int lane = tid & 63;
    const int p    = blockIdx.x * PPB + w;
    const int b    = p >> 11;
    const int n    = p & (NN - 1);

    const float* xb0 = x + (size_t)(b * 3 + 0) * NN;
    const float* xb1 = x + (size_t)(b * 3 + 1) * NN;
    const float* xb2 = x + (size_t)(b * 3 + 2) * NN;

    // ---- neighbor ids from the KNN kernel (wave-local LDS stage) ----
    if (lane < KK) nid_s[w][lane] = nid[(size_t)p * KK + lane];

    // ======= per-point pipeline: all wave-local, NO barriers needed =======
    fcol_s[w][lane] = featT[((size_t)b * NN + n) * CIN + lane];

    if (lane == 0) {
        int m0 = nid_s[w][0];
        xrep_s[w][0] = xb0[m0]; xrep_s[w][1] = xb1[m0]; xrep_s[w][2] = xb2[m0];
    }
    if (lane < KK) {
        int m = nid_s[w][lane];
        float rx = xb0[m] - xrep_s[w][0];
        float ry = xb1[m] - xrep_s[w][1];
        float rz = xb2[m] - xrep_s[w][2];
        xr_s[w][lane][0] = rx; xr_s[w][lane][1] = ry; xr_s[w][lane][2] = rz;
        xd_s[w][lane] = sqrtf(rx * rx + ry * ry + rz * rz + 1e-12f);
    }

    // ---- perm: relu -> colnorm -> square -> colnorm -> >0.1 (wave-local) --
    for (int e = lane; e < KK * KSS; e += 64) {
        int k = e / KSS, m = e % KSS;
        float v = xr_s[w][k][0] * kern[0 * KSS + m]
                + xr_s[w][k][1] * kern[1 * KSS + m]
                + xr_s[w][k][2] * kern[2 * KSS + m]
                + pad[k * KSS + m];
        perm_s[w][k][m] = v > 0.0f ? v : 0.0f;
    }
    if (lane < KSS) {
        float s = 0.0f;
        for (int k = 0; k < KK; ++k) s += perm_s[w][k][lane];
        colden_s[w][lane] = s + 1e-6f;
    }
    for (int e = lane; e < KK * KSS; e += 64) {
        int k = e / KSS, m = e % KSS;
        float v = perm_s[w][k][m] / colden_s[w][m];
        perm_s[w][k][m] = v * v;
    }
    if (lane < KSS) {
        float s = 0.0f;
        for (int k = 0; k < KK; ++k) s += perm_s[w][k][lane];
        colden_s[w][lane] = s + 1e-6f;
    }
    for (int e = lane; e < KK * KSS; e += 64) {
        int k = e / KSS, m = e % KSS;
        float v = perm_s[w][k][m] / colden_s[w][m];
        perm_s[w][k][m] = v > 0.1f ? v : 0.0f;
    }

    // ---- feats in registers (coalesced gathers from featT) ----
    float fg[KK], fm[KK];
#pragma unroll
    for (int k = 0; k < KK; ++k)
        fg[k] = featT[((size_t)b * NN + nid_s[w][k]) * CIN + lane];
    {
        float w0 = mlp_w[lane * 7 + 0], w1 = mlp_w[lane * 7 + 1];
        float w2 = mlp_w[lane * 7 + 2], w3 = mlp_w[lane * 7 + 3];
        float w4 = mlp_w[lane * 7 + 4], w5 = mlp_w[lane * 7 + 5];
        float w6 = mlp_w[lane * 7 + 6];
        float bias = mlp_b[lane];
#pragma unroll
        for (int k = 0; k < KK; ++k) {
            fm[k] = xrep_s[w][0] * w0 + xrep_s[w][1] * w1 + xrep_s[w][2] * w2
                  + xr_s[w][k][0] * w3 + xr_s[w][k][1] * w4 + xr_s[w][k][2] * w5
                  + xd_s[w][k] * w6 + bias;
        }
    }

    // ---- agg rows c=lane, c=64+lane; float4 perm reads (broadcast, free) --
#pragma unroll
    for (int m4 = 0; m4 < KSS / 4; ++m4) {
        float sx = 0.f, sy = 0.f, sz = 0.f, sw = 0.f;
        float tx = 0.f, ty = 0.f, tz = 0.f, tw = 0.f;
#pragma unroll
        for (int k = 0; k < KK; ++k) {
            const float4 pv = *(const float4*)&perm_s[w][k][m4 * 4];
            const float a = fg[k], c = fm[k];
            sx += a * pv.x; sy += a * pv.y; sz += a * pv.z; sw += a * pv.w;
            tx += c * pv.x; ty += c * pv.y; tz += c * pv.z; tw += c * pv.w;
        }
        const int mb = m4 * 4;
        agg_h[w][lane * KSS + mb + 0]         = (_Float16)sx;
        agg_h[w][lane * KSS + mb + 1]         = (_Float16)sy;
        agg_h[w][lane * KSS + mb + 2]         = (_Float16)sz;
        agg_h[w][lane * KSS + mb + 3]         = (_Float16)sw;
        agg_h[w][(CIN + lane) * KSS + mb + 0] = (_Float16)tx;
        agg_h[w][(CIN + lane) * KSS + mb + 1] = (_Float16)ty;
        agg_h[w][(CIN + lane) * KSS + mb + 2] = (_Float16)tz;
        agg_h[w][(CIN + lane) * KSS + mb + 3] = (_Float16)tw;
    }
    __syncthreads();   // BARRIER 1: cross-wave agg_h; perm_s -> red2 handoff

    // ---- cooperative conv on the MATRIX pipe: wave w = outputs 16w..16w+15
    {
        f32x4 acc0 = {0.f, 0.f, 0.f, 0.f};
        f32x4 acc1 = {0.f, 0.f, 0.f, 0.f};
        const uint4* ap = aFrag + (size_t)(w * KT) * 64 + lane;
        const _Float16* bp = &agg_h[lane & 3][(lane >> 4) * 8];
#pragma unroll 4
        for (int t = 0; t < KT; t += 2) {
            uint4 av0 = ap[(size_t)t * 64];
            uint4 av1 = ap[(size_t)(t + 1) * 64];
            f16x8 b0 = *(const f16x8*)(bp + t * 32);
            f16x8 b1 = *(const f16x8*)(bp + (t + 1) * 32);
            acc0 = __builtin_amdgcn_mfma_f32_16x16x32_f16(
                       __builtin_bit_cast(f16x8, av0), b0, acc0, 0, 0, 0);
            acc1 = __builtin_amdgcn_mfma_f32_16x16x32_f16(
                       __builtin_bit_cast(f16x8, av1), b1, acc1, 0, 0, 0);
        }
        acc0 += acc1;
        if ((lane & 15) < 4) {
            const int p2 = lane & 15;
            const int ob = (w << 4) + ((lane >> 4) << 2);
            *(f32x4*)&red2[p2][ob] = acc0;
        }
    }
    __syncthreads();   // BARRIER 2: cross-wave red2

    // ---- wave w finalizes point w ----
    {
        float acc = conv_b[lane] + red2[w][lane];
        for (int c = 0; c < CIN; ++c)
            acc += fcol_s[w][c] * mowT[c * COUT + lane];
        acc += mob[lane];
        out[(size_t)(b * COUT + lane) * NN + n] = acc;
    }
}

// ---------------------------------------------------------------------------
// BatchNorm split: 512-block reduce into partials, 512-block apply.
// ---------------------------------------------------------------------------
__global__ __launch_bounds__(256) void bn_reduce(
    const float* __restrict__ out, float* __restrict__ part)
{
    const int o = blockIdx.x >> 3;     // channel
    const int s = blockIdx.x & 7;      // batch index
    const float* src = out + (size_t)(s * COUT + o) * NN;
    float a = 0.f, q = 0.f;
    for (int i = threadIdx.x; i < NN; i += 256) {
        float v = src[i];
        a += v; q += v * v;
    }
    __shared__ float s1[256], s2[256];
    s1[threadIdx.x] = a; s2[threadIdx.x] = q;
    __syncthreads();
    for (int st = 128; st > 0; st >>= 1) {
        if (threadIdx.x < st) {
            s1[threadIdx.x] += s1[threadIdx.x + st];
            s2[threadIdx.x] += s2[threadIdx.x + st];
        }
        __syncthreads();
    }
    if (threadIdx.x == 0) {
        part[(o * 8 + s) * 2 + 0] = s1[0];
        part[(o * 8 + s) * 2 + 1] = s2[0];
    }
}

__global__ __launch_bounds__(256) void bn_apply(
    float* __restrict__ out, const float* __restrict__ part,
    const float* __restrict__ gamma, const float* __restrict__ beta)
{
    const int o = blockIdx.x >> 3;
    const int s = blockIdx.x & 7;
    float a = 0.f, q = 0.f;
#pragma unroll
    for (int t = 0; t < 8; ++t) {
        a += part[(o * 8 + t) * 2 + 0];
        q += part[(o * 8 + t) * 2 + 1];
    }
    const float M = (float)(BB * NN);
    const float mean = a / M;
    float var = q / M - mean * mean;
    if (var < 0.f) var = 0.f;
    const float inv = 1.0f / sqrtf(var + 1e-5f);
    const float g = gamma[o] * inv, be = beta[o];
    float* dst = out + (size_t)(s * COUT + o) * NN;
    for (int i = threadIdx.x; i < NN; i += 256) {
        dst[i] = (dst[i] - mean) * g + be;
    }
}

// ---------------------------------------------------------------------------
extern "C" void kernel_launch(void* const* d_in, const int* in_sizes, int n_in,
                              void* d_out, int out_size, void* d_ws, size_t ws_size,
                              hipStream_t stream)
{
    const float* x       = (const float*)d_in[0];
    const float* feature = (const float*)d_in[1];
    const float* kern    = (const float*)d_in[2];
    const float* pad     = (const float*)d_in[3];
    const float* mlp_w   = (const float*)d_in[4];
    const float* mlp_b   = (const float*)d_in[5];
    const float* conv_w  = (const float*)d_in[6];
    const float* conv_b  = (const float*)d_in[7];
    const float* mow     = (const float*)d_in[8];
    const float* mob     = (const float*)d_in[9];
    const float* gamma   = (const float*)d_in[10];
    const float* beta    = (const float*)d_in[11];

    char* wsp = (char*)d_ws;
    uint4* aFrag = (uint4*)wsp;                        // 327680 B
    float* mowT  = (float*)(wsp + 327680);             //  16384 B
    float* part  = (float*)(wsp + 327680 + 16384);     //   4096 B
    int*   nid   = (int*)(wsp + 327680 + 16384 + 4096);// 1310720 B
    float* featT = (float*)(wsp + 327680 + 16384 + 4096 + 1310720); // 4 MB

    float* out = (float*)d_out;

    prep_kernel<<<(4 * KT * 64 + 255) / 256, 256, 0, stream>>>(conv_w, mow, aFrag, mowT);
    tr_kernel<<<BB * (NN / 64), 256, 0, stream>>>(feature, featT);
    knn_kernel<<<BB * NN / 4, 256, 0, stream>>>(x, nid);
    point_kernel<<<BB * NN / PPB, 256, 0, stream>>>(x, featT, kern, pad,
                                                    mlp_w, mlp_b, aFrag, conv_b,
                                                    mowT, mob, nid, out);
    bn_reduce<<<512, 256, 0, stream>>>(out, part);
    bn_apply<<<512, 256, 0, stream>>>(out, part, gamma, beta);
}